// Round 2
// baseline (425.655 us; speedup 1.0000x reference)
//
#include <hip/hip_runtime.h>
#include <hip/hip_bf16.h>

#define QL 1024
#define KL 1024
#define HM 64
#define DD 128
#define SM_SCALE 0.08838834764831845f

typedef __bf16 bf16x8_t __attribute__((ext_vector_type(8)));
typedef __bf16 bf16x4_t __attribute__((ext_vector_type(4)));
typedef float floatx4_t __attribute__((ext_vector_type(4)));

__device__ __forceinline__ void async_cp16(const void* g, void* l) {
    __builtin_amdgcn_global_load_lds(
        (const __attribute__((address_space(1))) void*)g,
        (__attribute__((address_space(3))) void*)l, 16, 0, 0);
}

// ---------------- pass 1: fp32 [q][g][d] -> bf16 [g][q][d] ----------------
__global__ __launch_bounds__(256)
void cvt_kernel(const float* __restrict__ Q, const float* __restrict__ K,
                __bf16* __restrict__ Qb, __bf16* __restrict__ Kb)
{
    const int g = blockIdx.y, rc = blockIdx.x, t = threadIdx.x;
    const size_t inb  = (size_t)(rc * 128) * (HM * DD) + (size_t)g * DD;
    const size_t outb = (size_t)g * (QL * DD) + (size_t)(rc * 128) * DD;
#pragma unroll
    for (int j = 0; j < 16; ++j) {
        int c = t + 256 * j, row = c >> 5, c4 = c & 31;
        size_t go = inb + (size_t)row * (HM * DD) + c4 * 4;
        size_t wo = outb + (size_t)row * DD + c4 * 4;
        float4 a = *(const float4*)(Q + go);
        float4 b = *(const float4*)(K + go);
        bf16x4_t av = { (__bf16)a.x, (__bf16)a.y, (__bf16)a.z, (__bf16)a.w };
        bf16x4_t bv = { (__bf16)b.x, (__bf16)b.y, (__bf16)b.z, (__bf16)b.w };
        *(bf16x4_t*)(Qb + wo) = av;
        *(bf16x4_t*)(Kb + wo) = bv;
    }
}

// ---------------- pass 2: per (g, 128-q strip), loop over 8 k-tiles --------
// LDS swizzle: row r (256 B), 16-B slot s holds global chunk s ^ (r & 15).
__global__ __launch_bounds__(256, 2)
void qk2_kernel(const __bf16* __restrict__ Qb, const __bf16* __restrict__ Kb,
                const float* __restrict__ mask, const float* __restrict__ sinks,
                float* __restrict__ out)
{
    const int g  = blockIdx.y;
    const int qt = blockIdx.x * 128;

    __shared__ __bf16 As[128 * DD];
    __shared__ __bf16 Bs[128 * DD];

    const int t = threadIdx.x, wave = t >> 6, lane = t & 63;
    const int lr = lane & 15, quad = lane >> 4;
    const int wm = (wave & 1) * 64, wn = (wave >> 1) * 64;

    const __bf16* Atile  = Qb + (size_t)g * QL * DD + (size_t)qt * DD;
    const __bf16* Ktile0 = Kb + (size_t)g * KL * DD;

    // stage A (whole kernel) + B tile 0, swizzled, async
#pragma unroll
    for (int i = 0; i < 8; ++i) {
        int r = wave * 32 + i * 4 + (lane >> 4);
        int s = lane & 15;
        int c = s ^ (r & 15);
        async_cp16(Atile + (size_t)r * DD + c * 8, As + (wave * 32 + i * 4) * DD);
    }
#pragma unroll
    for (int i = 0; i < 8; ++i) {
        int r = wave * 32 + i * 4 + (lane >> 4);
        int s = lane & 15;
        int c = s ^ (r & 15);
        async_cp16(Ktile0 + (size_t)r * DD + c * 8, Bs + (wave * 32 + i * 4) * DD);
    }
    asm volatile("s_waitcnt vmcnt(0)" ::: "memory");
    __syncthreads();

    // hoisted A fragments: A[m=lr][k = ks*32 + quad*8 + j]
    bf16x8_t af[4][4];   // [ks][mi]
#pragma unroll
    for (int ks = 0; ks < 4; ++ks)
#pragma unroll
        for (int mi = 0; mi < 4; ++mi) {
            int r = wm + mi * 16 + lr;
            int c = ks * 4 + quad;          // r&15 == lr
            af[ks][mi] = *(const bf16x8_t*)&As[r * DD + (c ^ lr) * 8];
        }

    const size_t outg = (size_t)g * QL * 1025;

#pragma unroll 1
    for (int kt = 0; kt < 8; ++kt) {
        // pull B fragments into regs (frees Bs for async restage)
        bf16x8_t bfr[4][4];  // [ks][ni]
#pragma unroll
        for (int ks = 0; ks < 4; ++ks)
#pragma unroll
            for (int ni = 0; ni < 4; ++ni) {
                int r = wn + ni * 16 + lr;
                int c = ks * 4 + quad;
                bfr[ks][ni] = *(const bf16x8_t*)&Bs[r * DD + (c ^ lr) * 8];
            }
        __syncthreads();   // all waves done reading Bs

        if (kt < 7) {      // async restage of Bs overlaps MFMA + epilogue
            const __bf16* Kt = Ktile0 + (size_t)(kt + 1) * 128 * DD;
#pragma unroll
            for (int i = 0; i < 8; ++i) {
                int r = wave * 32 + i * 4 + (lane >> 4);
                int s = lane & 15;
                int c = s ^ (r & 15);
                async_cp16(Kt + (size_t)r * DD + c * 8, Bs + (wave * 32 + i * 4) * DD);
            }
        }

        floatx4_t acc[4][4] = {};
#pragma unroll
        for (int ks = 0; ks < 4; ++ks)
#pragma unroll
            for (int mi = 0; mi < 4; ++mi)
#pragma unroll
                for (int ni = 0; ni < 4; ++ni)
                    acc[mi][ni] = __builtin_amdgcn_mfma_f32_16x16x32_bf16(
                        af[ks][mi], bfr[ks][ni], acc[mi][ni], 0, 0, 0);

        // epilogue: C/D layout col=lane&15 (k), row=quad*4+r4 (q)
#pragma unroll
        for (int mi = 0; mi < 4; ++mi)
#pragma unroll
            for (int r4 = 0; r4 < 4; ++r4) {
                int q = qt + wm + mi * 16 + quad * 4 + r4;
                const float* mrow = mask + (size_t)q * KL + kt * 128;
                float* orow = out + outg + (size_t)q * 1025 + kt * 128;
#pragma unroll
                for (int ni = 0; ni < 4; ++ni) {
                    int k = wn + ni * 16 + lr;
                    orow[k] = acc[mi][ni][r4] * SM_SCALE + mrow[k];
                }
            }

        if (kt < 7) {
            asm volatile("s_waitcnt vmcnt(0)" ::: "memory");
            __syncthreads();   // restaged Bs visible to all waves
        }
    }

    // fused sink column: out[g][q][1024] = sinks[g][q]
    if (t < 128) {
        int q = qt + t;
        out[outg + (size_t)q * 1025 + 1024] = sinks[(size_t)g * QL + q];
    }
}

// ---------------- fallback path (v1, used only if ws too small) -----------
#define BM 128
#define BN 128
#define LDPAD 136

__global__ __launch_bounds__(256, 2)
void qk_kernel(const float* __restrict__ Qg, const float* __restrict__ Kg,
               const float* __restrict__ mask, float* __restrict__ out)
{
    const int g    = blockIdx.y;
    const int tile = blockIdx.x;
    const int qt = (tile >> 3) * BM;
    const int kt = (tile & 7) * BN;

    __shared__ __bf16 As[BM][LDPAD];
    __shared__ __bf16 Bs[BN][LDPAD];

    const int t = threadIdx.x;

    const float* Ag = Qg + (size_t)qt * (HM * DD) + (size_t)g * DD;
    const float* Bg = Kg + (size_t)kt * (HM * DD) + (size_t)g * DD;
#pragma unroll
    for (int j = 0; j < 16; ++j) {
        int c = t + 256 * j;
        int row = c >> 5;
        int c4  = c & 31;
        float4 a = *(const float4*)(Ag + (size_t)row * (HM * DD) + c4 * 4);
        float4 b = *(const float4*)(Bg + (size_t)row * (HM * DD) + c4 * 4);
        bf16x4_t av = { (__bf16)a.x, (__bf16)a.y, (__bf16)a.z, (__bf16)a.w };
        bf16x4_t bv = { (__bf16)b.x, (__bf16)b.y, (__bf16)b.z, (__bf16)b.w };
        *(bf16x4_t*)&As[row][c4 * 4] = av;
        *(bf16x4_t*)&Bs[row][c4 * 4] = bv;
    }
    __syncthreads();

    const int wave = t >> 6;
    const int lane = t & 63;
    const int wm = (wave & 1) * 64;
    const int wn = (wave >> 1) * 64;
    const int lr = lane & 15;
    const int quad = lane >> 4;

    floatx4_t acc[4][4] = {};

#pragma unroll
    for (int ks = 0; ks < 4; ++ks) {
        const int d0 = ks * 32 + quad * 8;
        bf16x8_t a8[4], b8[4];
#pragma unroll
        for (int mi = 0; mi < 4; ++mi)
            a8[mi] = *(const bf16x8_t*)&As[wm + mi * 16 + lr][d0];
#pragma unroll
        for (int ni = 0; ni < 4; ++ni)
            b8[ni] = *(const bf16x8_t*)&Bs[wn + ni * 16 + lr][d0];
#pragma unroll
        for (int mi = 0; mi < 4; ++mi)
#pragma unroll
            for (int ni = 0; ni < 4; ++ni)
                acc[mi][ni] = __builtin_amdgcn_mfma_f32_16x16x32_bf16(
                    a8[mi], b8[ni], acc[mi][ni], 0, 0, 0);
    }

    const size_t obase = (size_t)g * QL * 1025;
#pragma unroll
    for (int mi = 0; mi < 4; ++mi) {
#pragma unroll
        for (int r = 0; r < 4; ++r) {
            int q = qt + wm + mi * 16 + quad * 4 + r;
            const float* mrow = mask + (size_t)q * KL;
            float* orow = out + obase + (size_t)q * 1025;
#pragma unroll
            for (int ni = 0; ni < 4; ++ni) {
                int k = kt + wn + ni * 16 + lr;
                orow[k] = acc[mi][ni][r] * SM_SCALE + mrow[k];
            }
        }
    }
}

__global__ void sink_kernel(const float* __restrict__ sinks, float* __restrict__ out)
{
    int idx = blockIdx.x * 256 + threadIdx.x;
    out[(size_t)idx * 1025 + 1024] = sinks[idx];
}

extern "C" void kernel_launch(void* const* d_in, const int* in_sizes, int n_in,
                              void* d_out, int out_size, void* d_ws, size_t ws_size,
                              hipStream_t stream)
{
    const float* Q     = (const float*)d_in[0];
    const float* K     = (const float*)d_in[1];
    const float* mask  = (const float*)d_in[2];
    const float* sinks = (const float*)d_in[3];
    float* out = (float*)d_out;

    const size_t need = (size_t)2 * QL * HM * DD * sizeof(__bf16);  // 32 MiB
    if (ws_size >= need) {
        __bf16* Qb = (__bf16*)d_ws;
        __bf16* Kb = Qb + (size_t)QL * HM * DD;
        cvt_kernel<<<dim3(8, 64), 256, 0, stream>>>(Q, K, Qb, Kb);
        qk2_kernel<<<dim3(8, 64), 256, 0, stream>>>(Qb, Kb, mask, sinks, out);
    } else {
        sink_kernel<<<(HM * QL) / 256, 256, 0, stream>>>(sinks, out);
        qk_kernel<<<dim3(64, 64), 256, 0, stream>>>(Q, K, mask, out);
    }
}